// Round 27
// baseline (73.921 us; speedup 1.0000x reference)
//
#include <hip/hip_runtime.h>
#include <stdint.h>

#define N_ANCH 12288
#define NCLS 64
#define TOTW 192              // 64-box words in patch-sorted (s) space
#define CAPO 1024             // overflow (word,mask) slots per row

typedef unsigned long long u64;
typedef unsigned int u32;
typedef unsigned short u16;
typedef unsigned char u8;

// IoU > 0.5 predicate, replicating numpy op order/rounding exactly (no FMA contraction).
__device__ __forceinline__ bool iou_gt(float4 a, float fa, float4 b, float fb) {
    float xx1 = fmaxf(a.x, b.x);
    float yy1 = fmaxf(a.y, b.y);
    float xx2 = fminf(a.z, b.z);
    float yy2 = fminf(a.w, b.w);
    float dx = fmaxf(__fsub_rn(xx2, xx1), 0.0f);
    float dy = fmaxf(__fsub_rn(yy2, yy1), 0.0f);
    float inter = __fmul_rn(dx, dy);
    float denom = __fadd_rn(__fsub_rn(__fadd_rn(fa, fb), inter), 1e-9f);
    float iou = __fdiv_rn(inter, denom);
    return iou > 0.5f;
}
__device__ __forceinline__ float area_of(float4 b) {
    return __fmul_rn(__fsub_rn(b.z, b.x), __fsub_rn(b.w, b.y));
}

// s-space (patch-major) -> original index
__device__ __forceinline__ int orig_of(int s) {
    int w = s >> 6, l = s & 63;
    int py = w >> 4, px = w & 15, ly = l >> 3, lx = l & 7;
    return (((py << 3) + ly) << 7) + ((px << 3) + lx);
}

// ---------------- decode (s-order): pbox/pkey + wave-local hulls + segmented outliers ----------------
__global__ void decode_kernel(const float4* __restrict__ loc, const float* __restrict__ cls,
                              float4* __restrict__ boxes, float* __restrict__ score,
                              float4* __restrict__ pbox, u64* __restrict__ pkey,
                              u64* __restrict__ rec8, float4* __restrict__ wbg,
                              u32* __restrict__ ocnt, u16* __restrict__ olist) {
    int s = blockIdx.x * 256 + threadIdx.x;       // s-space index
    int lane = threadIdx.x & 63;
    int W = s >> 6;
    int i = orig_of(s);
    float4 l = loc[i];
    int y = i >> 7;        // FM_W = 128
    int x = i & 127;
    float cx = (x + 0.5f) * 8.0f;   // exact
    float cy = (y + 0.5f) * 8.0f;   // exact
    float px = __fadd_rn(__fmul_rn(l.x, 32.0f), cx);
    float py = __fadd_rn(__fmul_rn(l.y, 32.0f), cy);
    float pw = __fmul_rn(expf(l.z), 32.0f);
    float ph = __fmul_rn(expf(l.w), 32.0f);
    float hx = __fmul_rn(pw, 0.5f);
    float hy = __fmul_rn(ph, 0.5f);
    float x1 = __fsub_rn(px, hx), y1 = __fsub_rn(py, hy);
    float x2 = __fadd_rn(px, hx), y2 = __fadd_rn(py, hy);
    float4 b; b.x = x1; b.y = y1; b.z = x2; b.w = y2;
    boxes[i] = b;

    const float4* cr = (const float4*)(cls + (size_t)i * NCLS);
    float mx = -INFINITY;
#pragma unroll
    for (int k = 0; k < 16; ++k) {
        float4 v = cr[k];
        mx = fmaxf(mx, fmaxf(fmaxf(v.x, v.y), fmaxf(v.z, v.w)));
    }
    float sc;
    if (mx >= 0.0f) {
        float e = expf(-mx);
        sc = __fdiv_rn(1.0f, __fadd_rn(1.0f, e));
    } else {
        float e = expf(mx);
        sc = __fdiv_rn(e, __fadd_rn(1.0f, e));
    }
    score[i] = sc;
    float se = (sc > 0.5f) ? sc : -INFINITY;   // score_eff
    u32 u = __float_as_uint(se);
    u = (u & 0x80000000u) ? ~u : (u | 0x80000000u);   // ascending; valid >= 0x80000000

    bool valid = (u >= 0x80000000u);
    bool big = ((x2 - x1) > 128.0f) || ((y2 - y1) > 128.0f);
    pbox[s] = b;
    pkey[s] = ((u64)u << 32) | (u32)(~(u32)i);        // earlier(j,i) <=> k64_j > k64_i
    rec8[(size_t)s * 8] = 0ull;

    // wave-local trimmed hull (valid && !big), plain store — no atomics, no pre-zero
    bool inh = valid && !big;
    float ax1 = inh ? x1 : INFINITY;
    float ay1 = inh ? y1 : INFINITY;
    float ax2 = inh ? x2 : -INFINITY;
    float ay2 = inh ? y2 : -INFINITY;
#pragma unroll
    for (int off = 1; off < 64; off <<= 1) {
        ax1 = fminf(ax1, __shfl_xor(ax1, off));
        ay1 = fminf(ay1, __shfl_xor(ay1, off));
        ax2 = fmaxf(ax2, __shfl_xor(ax2, off));
        ay2 = fmaxf(ay2, __shfl_xor(ay2, off));
    }
    if (lane == 0) { float4 h; h.x = ax1; h.y = ay1; h.z = ax2; h.w = ay2; wbg[W] = h; }

    // segmented outlier list: word W's big boxes at olist[W*64 + rank]
    u64 bm = __ballot(valid && big);
    if (valid && big) {
        u32 rnk = (u32)__popcll(bm & ((1ull << lane) - 1ull));
        olist[(W << 6) + rnk] = (u16)s;
    }
    if (lane == 0) ocnt[W] = (u32)__popcll(bm);
}

// ---------------- pairs: windows -> LDS worklist -> prefetched wave exec -> outlier pass ----------------
// 768 blocks x 512 thr (~20KB LDS). Block bid owns 16 s-rows [bid*16, +16).
__global__ void __launch_bounds__(512)
pairs_kernel(const float4* __restrict__ pbox, const u64* __restrict__ pkey,
             u64* __restrict__ rec8, u8* __restrict__ ovw, u64* __restrict__ ovm,
             const float4* __restrict__ wbg, const u32* __restrict__ ocnt,
             const u16* __restrict__ olist,
             u64* __restrict__ keptg, u64* __restrict__ killedg) {
    __shared__ float4 rbox[16];  __shared__ u64 rk[16];
    __shared__ float4 wb[TOTW];
    __shared__ u32 sc[TOTW];     __shared__ u32 cns[TOTW];
    __shared__ u32 pcnt, ccnt;
    // 15.4KB arena: phase2 = pbuf[3072] u32 (12KB); phase3 = cobox/coarea/cokey/cosid (15.36KB)
    __shared__ __align__(16) u8 arena[15360];
    u32*    pbuf   = (u32*)arena;                      // 12288 B (3072 max pairs for 16 rows)
    float4* cobox  = (float4*)arena;                   // 8192 B
    float*  coarea = (float*)(arena + 8192);           // 2048 B
    u64*    cokey  = (u64*)(arena + 10240);            // 4096 B
    u16*    cosid  = (u16*)(arena + 14336);            // 1024 B

    int tid = threadIdx.x;
    int wave = tid >> 6, lane = tid & 63;      // 8 waves
    int bid = blockIdx.x;
    int rowbase = bid << 4;                    // 16 global s-rows

    if (bid == 0 && tid < TOTW) { keptg[tid] = 0ull; killedg[tid] = 0ull; }  // solve-only buffers
    if (tid == 0) pcnt = 0;
    if (tid < 16) {
        rbox[tid] = pbox[rowbase + tid];
        rk[tid] = pkey[rowbase + tid];
    }
    if (tid < TOTW) {
        wb[tid] = wbg[tid];                    // empty word -> (inf,inf,-inf,-inf) -> never passes
        u32 c = ocnt[tid];
        cns[tid] = c;
        sc[tid] = c;
    }
    __syncthreads();
    // inclusive prefix scan of outlier counts (192 entries, Hillis-Steele)
    for (int off = 1; off < TOTW; off <<= 1) {
        u32 v = 0;
        if (tid < TOTW && tid >= off) v = sc[tid - off];
        __syncthreads();
        if (tid < TOTW && tid >= off) sc[tid] += v;
        __syncthreads();
    }
    u32 ocn = sc[TOTW - 1];

    // block hull over this block's 16 rows (valid rows incl big)
    float4 bh;
    {
        int rl = lane & 15;
        float4 b = rbox[rl];
        bool valid = (rk[rl] >> 63) != 0ull;
        float ax1 = valid ? b.x : INFINITY;
        float ay1 = valid ? b.y : INFINITY;
        float ax2 = valid ? b.z : -INFINITY;
        float ay2 = valid ? b.w : -INFINITY;
#pragma unroll
        for (int off = 1; off < 16; off <<= 1) {
            ax1 = fminf(ax1, __shfl_xor(ax1, off));
            ay1 = fminf(ay1, __shfl_xor(ay1, off));
            ax2 = fmaxf(ax2, __shfl_xor(ax2, off));
            ay2 = fmaxf(ay2, __shfl_xor(ay2, off));
        }
        bh.x = ax1; bh.y = ay1; bh.z = ax2; bh.w = ay2;
    }

    // windows: 16 rows x 192 trimmed hulls -> LDS worklist (wave-aggregated offsets)
    {
        int row = tid >> 5, wq = tid & 31;     // 16 rows x 32 word-groups of 6
        float4 bi = rbox[row];
        bool v = (rk[row] >> 63) != 0ull;
        u32 pm = 0;
#pragma unroll
        for (int k = 0; k < 6; ++k) {
            int W = wq * 6 + k;
            float4 h = wb[W];
            bool pass = v && (bi.x < h.z) && (h.x < bi.z) && (bi.y < h.w) && (h.y < bi.w);
            pm |= ((u32)pass) << k;
        }
        u32 nl = (u32)__popc(pm);
        // wave inclusive scan of nl
        u32 incl = nl;
#pragma unroll
        for (int d = 1; d < 64; d <<= 1) {
            u32 v2 = __shfl_up(incl, d);
            if (lane >= d) incl += v2;
        }
        u32 wtot = __shfl(incl, 63);
        u32 wbase = 0;
        if (lane == 63 && wtot) wbase = atomicAdd(&pcnt, wtot);
        wbase = __shfl(wbase, 63);
        u32 dst = wbase + incl - nl;
        u32 rsh = ((u32)row) << 8;
        while (pm) {
            int k = __ffs(pm) - 1; pm &= pm - 1;
            pbuf[dst++] = rsh | (u32)(wq * 6 + k);
        }
    }
    __syncthreads();

    // in-block pair exec: 8 waves grid-stride, depth-2 register prefetch
    {
        u32 n = pcnt;
        u32 t = wave;
        u32 e_cur = 0; float4 bj_cur; u64 kj_cur;
        if (t < n) {
            e_cur = pbuf[t];
            int j = (int)((e_cur & 255u) << 6) + lane;
            bj_cur = pbox[j]; kj_cur = pkey[j];
        }
        while (t < n) {
            u32 tn = t + 8;
            u32 e_nxt = 0; float4 bj_nxt; u64 kj_nxt;
            if (tn < n) {
                e_nxt = pbuf[tn];
                int j = (int)((e_nxt & 255u) << 6) + lane;
                bj_nxt = pbox[j]; kj_nxt = pkey[j];
            }
            u32 row = e_cur >> 8;
            u32 W = e_cur & 255u;
            float4 bi = rbox[row];             // LDS broadcast
            u64 ki = rk[row];
            float ai = area_of(bi);
            bool pred = (kj_cur > ki) && iou_gt(bi, ai, bj_cur, area_of(bj_cur));
            u64 mm = __ballot(pred);
            if (lane == 0 && mm) {
                int r = rowbase + (int)row;
                u32 slot = atomicAdd((u32*)&rec8[(size_t)r * 8], 1u);
                if (slot < 6) {
                    ((u8*)&rec8[(size_t)r * 8 + 1])[slot] = (u8)W;
                    rec8[(size_t)r * 8 + 2 + slot] = mm;
                } else if (slot < 6u + CAPO) {
                    ovw[(size_t)r * CAPO + slot - 6] = (u8)W;
                    ovm[(size_t)r * CAPO + slot - 6] = mm;
                }
            }
            e_cur = e_nxt; bj_cur = bj_nxt; kj_cur = kj_nxt; t = tn;
        }
    }

    // outlier pass: segmented gather -> reg-side hull prefilter -> ballot compaction -> rows x survivors
    for (u32 base = 0; base < ocn; base += 512) {
        u32 cnt = (ocn - base < 512u) ? (ocn - base) : 512u;
        __syncthreads();                   // protect prior phase's arena reads
        if (tid == 0) ccnt = 0;
        __syncthreads();                   // ccnt reset visible
        bool hit = false;
        float4 b;
        u64 k;
        u16 sj = 0;
        if (tid < cnt) {
            u32 g = base + tid;
            u32 lo = 0, hi = TOTW - 1;     // smallest w with sc[w] > g
            while (lo < hi) { u32 mid = (lo + hi) >> 1; if (sc[mid] > g) hi = mid; else lo = mid + 1; }
            u32 woff = g - (sc[lo] - cns[lo]);
            sj = olist[(lo << 6) + woff];
            b = pbox[sj];
            k = pkey[sj];
            hit = (b.x < bh.z) && (bh.x < b.z) && (b.y < bh.w) && (bh.y < b.w);
        }
        u64 bm = __ballot(hit);
        if (bm) {
            u32 wbs = 0;
            if (lane == 0) wbs = atomicAdd(&ccnt, (u32)__popcll(bm));
            wbs = __shfl(wbs, 0);
            if (hit) {
                u32 rnk = (u32)__popcll(bm & ((1ull << lane) - 1ull));
                u32 p = wbs + rnk;
                cobox[p] = b; coarea[p] = area_of(b); cokey[p] = k; cosid[p] = sj;
            }
        }
        __syncthreads();                   // compacted arrays final
        u32 cc = ccnt;
        for (int rr = 0; rr < 2; ++rr) {
            int row = wave * 2 + rr;       // 0..15
            u64 ki = rk[row];
            if (!(ki >> 63)) continue;     // invalid row: wave-uniform skip
            float4 bi = rbox[row];
            float ai = area_of(bi);
            for (u32 j0 = 0; j0 < cc; j0 += 64) {
                u32 jj = j0 + lane;
                bool pred = false;
                u16 so = 0;
                if (jj < cc) {
                    so = cosid[jj];
                    pred = (cokey[jj] > ki) && iou_gt(bi, ai, cobox[jj], coarea[jj]);
                }
                if (pred) {
                    int r = rowbase + row;
                    u32 slot = atomicAdd((u32*)&rec8[(size_t)r * 8], 1u);
                    u8 Wo = (u8)(so >> 6);
                    u64 mm = 1ull << (so & 63);
                    if (slot < 6) {
                        ((u8*)&rec8[(size_t)r * 8 + 1])[slot] = Wo;
                        rec8[(size_t)r * 8 + 2 + slot] = mm;
                    } else if (slot < 6u + CAPO) {
                        ovw[(size_t)r * CAPO + slot - 6] = Wo;
                        ovm[(size_t)r * CAPO + slot - 6] = mm;
                    }
                }
            }
        }
    }
}

// ---------------- solve: 12-block monotone fixpoint; global bitmaps, LDS snapshots ----------------
__global__ void __launch_bounds__(1024)
solve_kernel(const u64* __restrict__ rec8, const u8* __restrict__ ovw,
             const u64* __restrict__ ovm, const float4* __restrict__ boxes,
             const float* __restrict__ score, const u64* __restrict__ pkey,
             u64* __restrict__ keptg, u64* __restrict__ killedg,
             float* __restrict__ out) {
    __shared__ u64 ks[TOTW];
    __shared__ u64 kls[TOTW];
    __shared__ int nund;
    int tid = threadIdx.x;
    int i = blockIdx.x * 1024 + tid;       // s-space row, 1 row/thread
    u64 mybit = 1ull << (i & 63);
    int myw = i >> 6;

    const ulonglong4* rp = (const ulonglong4*)&rec8[(size_t)i * 8];
    ulonglong4 RA = rp[0];
    ulonglong4 RB = rp[1];
    u32 wc = (u32)RA.x;
    u64 wbts = RA.y;
    u64 m0 = RA.z, m1 = RA.w, m2 = RB.x, m3 = RB.y, m4 = RB.z, m5 = RB.w;
    u32 wcf = (wc <= 6u + CAPO) ? wc : (6u + CAPO);
    u32 w0 = (u32)(wbts & 0xFF), w1 = (u32)((wbts >> 8) & 0xFF), w2 = (u32)((wbts >> 16) & 0xFF);
    u32 w3 = (u32)((wbts >> 24) & 0xFF), w4 = (u32)((wbts >> 32) & 0xFF), w5 = (u32)((wbts >> 40) & 0xFF);

    bool valid = (pkey[i] >> 63) != 0ull;
    bool undec = valid;
    bool keepfl = false;
    if (!valid) atomicOr(&killedg[myw], mybit);

    for (int round = 0; round < 13000; ++round) {
        __syncthreads();
        if (tid < TOTW) ks[tid] = atomicOr(&keptg[tid], 0ull);
        else if (tid < 2 * TOTW) kls[tid - TOTW] = atomicOr(&killedg[tid - TOTW], 0ull);
        if (tid == 0) nund = 0;
        __syncthreads();
#pragma unroll 1
        for (int inner = 0; inner < 4; ++inner) {
            if (undec) {
                u64 anyk = 0, anyu = 0;
                if (wcf > 0) { u64 k = ks[w0], kl = kls[w0]; anyk |= m0 & k; anyu |= m0 & ~(k | kl); }
                if (wcf > 1) { u64 k = ks[w1], kl = kls[w1]; anyk |= m1 & k; anyu |= m1 & ~(k | kl); }
                if (wcf > 2) { u64 k = ks[w2], kl = kls[w2]; anyk |= m2 & k; anyu |= m2 & ~(k | kl); }
                if (wcf > 3) { u64 k = ks[w3], kl = kls[w3]; anyk |= m3 & k; anyu |= m3 & ~(k | kl); }
                if (wcf > 4) { u64 k = ks[w4], kl = kls[w4]; anyk |= m4 & k; anyu |= m4 & ~(k | kl); }
                if (wcf > 5) { u64 k = ks[w5], kl = kls[w5]; anyk |= m5 & k; anyu |= m5 & ~(k | kl); }
                for (u32 kk = 6; kk < wcf; ++kk) {
                    u32 Wo = ovw[(size_t)i * CAPO + (kk - 6)];
                    u64 mo = ovm[(size_t)i * CAPO + (kk - 6)];
                    u64 k = ks[Wo], kl = kls[Wo];
                    anyk |= mo & k; anyu |= mo & ~(k | kl);
                }
                if (anyk) {
                    undec = false;
                    atomicOr(&killedg[myw], mybit);
                    atomicOr(&kls[myw], mybit);
                } else if (!anyu) {
                    undec = false;
                    keepfl = true;
                    atomicOr(&keptg[myw], mybit);
                    atomicOr(&ks[myw], mybit);
                }
            }
            __syncthreads();
        }
        if (undec) atomicAdd(&nund, 1);
        __syncthreads();
        if (nund == 0) break;
    }

    int og = orig_of(i);
    float m = keepfl ? 1.0f : 0.0f;
    float4 bx = boxes[og];
    float s = score[og];
    out[(size_t)og * 5 + 0] = __fmul_rn(bx.x, m);
    out[(size_t)og * 5 + 1] = __fmul_rn(bx.y, m);
    out[(size_t)og * 5 + 2] = __fmul_rn(bx.z, m);
    out[(size_t)og * 5 + 3] = __fmul_rn(bx.w, m);
    out[(size_t)og * 5 + 4] = __fmul_rn(s, m);
}

extern "C" void kernel_launch(void* const* d_in, const int* in_sizes, int n_in,
                              void* d_out, int out_size, void* d_ws, size_t ws_size,
                              hipStream_t stream) {
    const float4* loc = (const float4*)d_in[0];
    const float* cls = (const float*)d_in[1];
    char* ws = (char*)d_ws;

    float4* boxes   = (float4*)(ws + 0);           // 196608
    float*  score   = (float*) (ws + 196608);      // 49152
    float4* pbox    = (float4*)(ws + 245760);      // 196608
    u64*    pkey    = (u64*)   (ws + 442368);      // 98304
    u64*    rec8    = (u64*)   (ws + 540672);      // 786432
    u64*    keptg   = (u64*)   (ws + 1327104);     // 1536
    u64*    killedg = (u64*)   (ws + 1328640);     // 1536
    float4* wbg     = (float4*)(ws + 1330176);     // 3072
    u32*    ocnt    = (u32*)   (ws + 1333248);     // 768
    u16*    olist   = (u16*)   (ws + 1334080);     // 24576 (192*64 u16)
    u8*     ovw     = (u8*)    (ws + 1358656);     // 12582912
    u64*    ovm     = (u64*)   (ws + 13941568);    // 100663296 (end ~114.6MB; ws ~256MB)
    float*  out     = (float*)d_out;

    decode_kernel<<<48, 256, 0, stream>>>(loc, cls, boxes, score, pbox, pkey, rec8,
                                          wbg, ocnt, olist);
    pairs_kernel<<<768, 512, 0, stream>>>(pbox, pkey, rec8, ovw, ovm,
                                          wbg, ocnt, olist, keptg, killedg);
    solve_kernel<<<12, 1024, 0, stream>>>(rec8, ovw, ovm, boxes, score, pkey,
                                          keptg, killedg, out);
}

// Round 28
// 72.726 us; speedup vs baseline: 1.0164x; 1.0164x over previous
//
#include <hip/hip_runtime.h>
#include <stdint.h>

#define N_ANCH 12288
#define NCLS 64
#define TOTW 192              // 64-box words in patch-sorted (s) space
#define CAPO 1024             // overflow (word,mask) slots per row

typedef unsigned long long u64;
typedef unsigned int u32;
typedef unsigned short u16;
typedef unsigned char u8;

// IoU > 0.5 predicate, replicating numpy op order/rounding exactly (no FMA contraction).
__device__ __forceinline__ bool iou_gt(float4 a, float fa, float4 b, float fb) {
    float xx1 = fmaxf(a.x, b.x);
    float yy1 = fmaxf(a.y, b.y);
    float xx2 = fminf(a.z, b.z);
    float yy2 = fminf(a.w, b.w);
    float dx = fmaxf(__fsub_rn(xx2, xx1), 0.0f);
    float dy = fmaxf(__fsub_rn(yy2, yy1), 0.0f);
    float inter = __fmul_rn(dx, dy);
    float denom = __fadd_rn(__fsub_rn(__fadd_rn(fa, fb), inter), 1e-9f);
    float iou = __fdiv_rn(inter, denom);
    return iou > 0.5f;
}
__device__ __forceinline__ float area_of(float4 b) {
    return __fmul_rn(__fsub_rn(b.z, b.x), __fsub_rn(b.w, b.y));
}

// s-space (patch-major) -> original index
__device__ __forceinline__ int orig_of(int s) {
    int w = s >> 6, l = s & 63;
    int py = w >> 4, px = w & 15, ly = l >> 3, lx = l & 7;
    return (((py << 3) + ly) << 7) + ((px << 3) + lx);
}

// ---------------- decode (s-order): pbox/pkey + wave-local hulls + segmented outliers ----------------
__global__ void decode_kernel(const float4* __restrict__ loc, const float* __restrict__ cls,
                              float4* __restrict__ boxes, float* __restrict__ score,
                              float4* __restrict__ pbox, u64* __restrict__ pkey,
                              u64* __restrict__ rec8, float4* __restrict__ wbg,
                              u32* __restrict__ ocnt, u16* __restrict__ olist) {
    int s = blockIdx.x * 256 + threadIdx.x;       // s-space index
    int lane = threadIdx.x & 63;
    int W = s >> 6;
    int i = orig_of(s);
    float4 l = loc[i];
    int y = i >> 7;        // FM_W = 128
    int x = i & 127;
    float cx = (x + 0.5f) * 8.0f;   // exact
    float cy = (y + 0.5f) * 8.0f;   // exact
    float px = __fadd_rn(__fmul_rn(l.x, 32.0f), cx);
    float py = __fadd_rn(__fmul_rn(l.y, 32.0f), cy);
    float pw = __fmul_rn(expf(l.z), 32.0f);
    float ph = __fmul_rn(expf(l.w), 32.0f);
    float hx = __fmul_rn(pw, 0.5f);
    float hy = __fmul_rn(ph, 0.5f);
    float x1 = __fsub_rn(px, hx), y1 = __fsub_rn(py, hy);
    float x2 = __fadd_rn(px, hx), y2 = __fadd_rn(py, hy);
    float4 b; b.x = x1; b.y = y1; b.z = x2; b.w = y2;
    boxes[i] = b;

    const float4* cr = (const float4*)(cls + (size_t)i * NCLS);
    float mx = -INFINITY;
#pragma unroll
    for (int k = 0; k < 16; ++k) {
        float4 v = cr[k];
        mx = fmaxf(mx, fmaxf(fmaxf(v.x, v.y), fmaxf(v.z, v.w)));
    }
    float sc;
    if (mx >= 0.0f) {
        float e = expf(-mx);
        sc = __fdiv_rn(1.0f, __fadd_rn(1.0f, e));
    } else {
        float e = expf(mx);
        sc = __fdiv_rn(e, __fadd_rn(1.0f, e));
    }
    score[i] = sc;
    float se = (sc > 0.5f) ? sc : -INFINITY;   // score_eff
    u32 u = __float_as_uint(se);
    u = (u & 0x80000000u) ? ~u : (u | 0x80000000u);   // ascending; valid >= 0x80000000

    bool valid = (u >= 0x80000000u);
    bool big = ((x2 - x1) > 128.0f) || ((y2 - y1) > 128.0f);
    pbox[s] = b;
    pkey[s] = ((u64)u << 32) | (u32)(~(u32)i);        // earlier(j,i) <=> k64_j > k64_i
    rec8[(size_t)s * 8] = 0ull;

    // wave-local trimmed hull (valid && !big), plain store — no atomics, no pre-zero
    bool inh = valid && !big;
    float ax1 = inh ? x1 : INFINITY;
    float ay1 = inh ? y1 : INFINITY;
    float ax2 = inh ? x2 : -INFINITY;
    float ay2 = inh ? y2 : -INFINITY;
#pragma unroll
    for (int off = 1; off < 64; off <<= 1) {
        ax1 = fminf(ax1, __shfl_xor(ax1, off));
        ay1 = fminf(ay1, __shfl_xor(ay1, off));
        ax2 = fmaxf(ax2, __shfl_xor(ax2, off));
        ay2 = fmaxf(ay2, __shfl_xor(ay2, off));
    }
    if (lane == 0) { float4 h; h.x = ax1; h.y = ay1; h.z = ax2; h.w = ay2; wbg[W] = h; }

    // segmented outlier list: word W's big boxes at olist[W*64 + rank]
    u64 bm = __ballot(valid && big);
    if (valid && big) {
        u32 rnk = (u32)__popcll(bm & ((1ull << lane) - 1ull));
        olist[(W << 6) + rnk] = (u16)s;
    }
    if (lane == 0) ocnt[W] = (u32)__popcll(bm);
}

// ---------------- pairs: windows -> LDS worklist -> prefetched wave exec -> outlier pass ----------------
// 768 blocks x 512 thr (~20KB LDS). Block bid owns 16 s-rows [bid*16, +16).
__global__ void __launch_bounds__(512)
pairs_kernel(const float4* __restrict__ pbox, const u64* __restrict__ pkey,
             u64* __restrict__ rec8, u8* __restrict__ ovw, u64* __restrict__ ovm,
             const float4* __restrict__ wbg, const u32* __restrict__ ocnt,
             const u16* __restrict__ olist,
             u64* __restrict__ keptg, u64* __restrict__ killedg) {
    __shared__ float4 rbox[16];  __shared__ u64 rk[16];
    __shared__ float4 wb[TOTW];
    __shared__ u32 sc[TOTW];     __shared__ u32 cns[TOTW];
    __shared__ u32 pcnt, ccnt;
    // 15.4KB arena: phase2 = pbuf[3072] u32 (12KB); phase3 = cobox/coarea/cokey/cosid (15.36KB)
    __shared__ __align__(16) u8 arena[15360];
    u32*    pbuf   = (u32*)arena;                      // 12288 B (3072 max pairs for 16 rows)
    float4* cobox  = (float4*)arena;                   // 8192 B
    float*  coarea = (float*)(arena + 8192);           // 2048 B
    u64*    cokey  = (u64*)(arena + 10240);            // 4096 B
    u16*    cosid  = (u16*)(arena + 14336);            // 1024 B

    int tid = threadIdx.x;
    int wave = tid >> 6, lane = tid & 63;      // 8 waves
    int bid = blockIdx.x;
    int rowbase = bid << 4;                    // 16 global s-rows

    if (bid == 0 && tid < TOTW) { keptg[tid] = 0ull; killedg[tid] = 0ull; }  // solve-only buffers
    if (tid == 0) pcnt = 0;
    if (tid < 16) {
        rbox[tid] = pbox[rowbase + tid];
        rk[tid] = pkey[rowbase + tid];
    }
    if (tid < TOTW) {
        wb[tid] = wbg[tid];                    // empty word -> (inf,inf,-inf,-inf) -> never passes
        cns[tid] = ocnt[tid];
    }
    // wave 0: barrier-free inclusive prefix scan of ocnt (192 = 3x64 shfl segments)
    if (wave == 0) {
        u32 a = ocnt[lane], b2 = ocnt[64 + lane], c2 = ocnt[128 + lane];
#pragma unroll
        for (int d = 1; d < 64; d <<= 1) {
            u32 va = __shfl_up(a, d), vb = __shfl_up(b2, d), vc = __shfl_up(c2, d);
            if (lane >= d) { a += va; b2 += vb; c2 += vc; }
        }
        u32 ta = __shfl(a, 63);
        u32 tb = __shfl(b2, 63);
        sc[lane] = a;
        sc[64 + lane] = ta + b2;
        sc[128 + lane] = ta + tb + c2;
    }
    __syncthreads();
    u32 ocn = sc[TOTW - 1];

    // block hull over this block's 16 rows (valid rows incl big)
    float4 bh;
    {
        int rl = lane & 15;
        float4 b = rbox[rl];
        bool valid = (rk[rl] >> 63) != 0ull;
        float ax1 = valid ? b.x : INFINITY;
        float ay1 = valid ? b.y : INFINITY;
        float ax2 = valid ? b.z : -INFINITY;
        float ay2 = valid ? b.w : -INFINITY;
#pragma unroll
        for (int off = 1; off < 16; off <<= 1) {
            ax1 = fminf(ax1, __shfl_xor(ax1, off));
            ay1 = fminf(ay1, __shfl_xor(ay1, off));
            ax2 = fmaxf(ax2, __shfl_xor(ax2, off));
            ay2 = fmaxf(ay2, __shfl_xor(ay2, off));
        }
        bh.x = ax1; bh.y = ay1; bh.z = ax2; bh.w = ay2;
    }

    // windows: 16 rows x 192 trimmed hulls -> LDS worklist (wave-aggregated offsets)
    {
        int row = tid >> 5, wq = tid & 31;     // 16 rows x 32 word-groups of 6
        float4 bi = rbox[row];
        bool v = (rk[row] >> 63) != 0ull;
        u32 pm = 0;
#pragma unroll
        for (int k = 0; k < 6; ++k) {
            int W = wq * 6 + k;
            float4 h = wb[W];
            bool pass = v && (bi.x < h.z) && (h.x < bi.z) && (bi.y < h.w) && (h.y < bi.w);
            pm |= ((u32)pass) << k;
        }
        u32 nl = (u32)__popc(pm);
        // wave inclusive scan of nl
        u32 incl = nl;
#pragma unroll
        for (int d = 1; d < 64; d <<= 1) {
            u32 v2 = __shfl_up(incl, d);
            if (lane >= d) incl += v2;
        }
        u32 wtot = __shfl(incl, 63);
        u32 wbase = 0;
        if (lane == 63 && wtot) wbase = atomicAdd(&pcnt, wtot);
        wbase = __shfl(wbase, 63);
        u32 dst = wbase + incl - nl;
        u32 rsh = ((u32)row) << 8;
        while (pm) {
            int k = __ffs(pm) - 1; pm &= pm - 1;
            pbuf[dst++] = rsh | (u32)(wq * 6 + k);
        }
    }
    __syncthreads();

    // in-block pair exec: 8 waves grid-stride, depth-2 register prefetch
    {
        u32 n = pcnt;
        u32 t = wave;
        u32 e_cur = 0; float4 bj_cur; u64 kj_cur;
        if (t < n) {
            e_cur = pbuf[t];
            int j = (int)((e_cur & 255u) << 6) + lane;
            bj_cur = pbox[j]; kj_cur = pkey[j];
        }
        while (t < n) {
            u32 tn = t + 8;
            u32 e_nxt = 0; float4 bj_nxt; u64 kj_nxt;
            if (tn < n) {
                e_nxt = pbuf[tn];
                int j = (int)((e_nxt & 255u) << 6) + lane;
                bj_nxt = pbox[j]; kj_nxt = pkey[j];
            }
            u32 row = e_cur >> 8;
            u32 W = e_cur & 255u;
            float4 bi = rbox[row];             // LDS broadcast
            u64 ki = rk[row];
            float ai = area_of(bi);
            bool pred = (kj_cur > ki) && iou_gt(bi, ai, bj_cur, area_of(bj_cur));
            u64 mm = __ballot(pred);
            if (lane == 0 && mm) {
                int r = rowbase + (int)row;
                u32 slot = atomicAdd((u32*)&rec8[(size_t)r * 8], 1u);
                if (slot < 6) {
                    ((u8*)&rec8[(size_t)r * 8 + 1])[slot] = (u8)W;
                    rec8[(size_t)r * 8 + 2 + slot] = mm;
                } else if (slot < 6u + CAPO) {
                    ovw[(size_t)r * CAPO + slot - 6] = (u8)W;
                    ovm[(size_t)r * CAPO + slot - 6] = mm;
                }
            }
            e_cur = e_nxt; bj_cur = bj_nxt; kj_cur = kj_nxt; t = tn;
        }
    }

    // outlier pass: segmented gather -> reg-side hull prefilter -> ballot compaction -> rows x survivors
    for (u32 base = 0; base < ocn; base += 512) {
        u32 cnt = (ocn - base < 512u) ? (ocn - base) : 512u;
        __syncthreads();                   // protect prior phase's arena reads
        if (tid == 0) ccnt = 0;
        __syncthreads();                   // ccnt reset visible
        bool hit = false;
        float4 b;
        u64 k;
        u16 sj = 0;
        if (tid < cnt) {
            u32 g = base + tid;
            u32 lo = 0, hi = TOTW - 1;     // smallest w with sc[w] > g
            while (lo < hi) { u32 mid = (lo + hi) >> 1; if (sc[mid] > g) hi = mid; else lo = mid + 1; }
            u32 woff = g - (sc[lo] - cns[lo]);
            sj = olist[(lo << 6) + woff];
            b = pbox[sj];
            k = pkey[sj];
            hit = (b.x < bh.z) && (bh.x < b.z) && (b.y < bh.w) && (bh.y < b.w);
        }
        u64 bm = __ballot(hit);
        if (bm) {
            u32 wbs = 0;
            if (lane == 0) wbs = atomicAdd(&ccnt, (u32)__popcll(bm));
            wbs = __shfl(wbs, 0);
            if (hit) {
                u32 rnk = (u32)__popcll(bm & ((1ull << lane) - 1ull));
                u32 p = wbs + rnk;
                cobox[p] = b; coarea[p] = area_of(b); cokey[p] = k; cosid[p] = sj;
            }
        }
        __syncthreads();                   // compacted arrays final
        u32 cc = ccnt;
        for (int rr = 0; rr < 2; ++rr) {
            int row = wave * 2 + rr;       // 0..15
            u64 ki = rk[row];
            if (!(ki >> 63)) continue;     // invalid row: wave-uniform skip
            float4 bi = rbox[row];
            float ai = area_of(bi);
            for (u32 j0 = 0; j0 < cc; j0 += 64) {
                u32 jj = j0 + lane;
                bool pred = false;
                u16 so = 0;
                if (jj < cc) {
                    so = cosid[jj];
                    pred = (cokey[jj] > ki) && iou_gt(bi, ai, cobox[jj], coarea[jj]);
                }
                if (pred) {
                    int r = rowbase + row;
                    u32 slot = atomicAdd((u32*)&rec8[(size_t)r * 8], 1u);
                    u8 Wo = (u8)(so >> 6);
                    u64 mm = 1ull << (so & 63);
                    if (slot < 6) {
                        ((u8*)&rec8[(size_t)r * 8 + 1])[slot] = Wo;
                        rec8[(size_t)r * 8 + 2 + slot] = mm;
                    } else if (slot < 6u + CAPO) {
                        ovw[(size_t)r * CAPO + slot - 6] = Wo;
                        ovm[(size_t)r * CAPO + slot - 6] = mm;
                    }
                }
            }
        }
    }
}

// ---------------- solve: 12-block monotone fixpoint; global bitmaps, LDS snapshots ----------------
__global__ void __launch_bounds__(1024)
solve_kernel(const u64* __restrict__ rec8, const u8* __restrict__ ovw,
             const u64* __restrict__ ovm, const float4* __restrict__ boxes,
             const float* __restrict__ score, const u64* __restrict__ pkey,
             u64* __restrict__ keptg, u64* __restrict__ killedg,
             float* __restrict__ out) {
    __shared__ u64 ks[TOTW];
    __shared__ u64 kls[TOTW];
    __shared__ int nund;
    int tid = threadIdx.x;
    int i = blockIdx.x * 1024 + tid;       // s-space row, 1 row/thread
    u64 mybit = 1ull << (i & 63);
    int myw = i >> 6;

    const ulonglong4* rp = (const ulonglong4*)&rec8[(size_t)i * 8];
    ulonglong4 RA = rp[0];
    ulonglong4 RB = rp[1];
    u32 wc = (u32)RA.x;
    u64 wbts = RA.y;
    u64 m0 = RA.z, m1 = RA.w, m2 = RB.x, m3 = RB.y, m4 = RB.z, m5 = RB.w;
    u32 wcf = (wc <= 6u + CAPO) ? wc : (6u + CAPO);
    u32 w0 = (u32)(wbts & 0xFF), w1 = (u32)((wbts >> 8) & 0xFF), w2 = (u32)((wbts >> 16) & 0xFF);
    u32 w3 = (u32)((wbts >> 24) & 0xFF), w4 = (u32)((wbts >> 32) & 0xFF), w5 = (u32)((wbts >> 40) & 0xFF);

    bool valid = (pkey[i] >> 63) != 0ull;
    bool undec = valid;
    bool keepfl = false;
    if (!valid) atomicOr(&killedg[myw], mybit);

    for (int round = 0; round < 13000; ++round) {
        __syncthreads();
        if (tid < TOTW) ks[tid] = atomicOr(&keptg[tid], 0ull);
        else if (tid < 2 * TOTW) kls[tid - TOTW] = atomicOr(&killedg[tid - TOTW], 0ull);
        if (tid == 0) nund = 0;
        __syncthreads();
#pragma unroll 1
        for (int inner = 0; inner < 4; ++inner) {
            if (undec) {
                u64 anyk = 0, anyu = 0;
                if (wcf > 0) { u64 k = ks[w0], kl = kls[w0]; anyk |= m0 & k; anyu |= m0 & ~(k | kl); }
                if (wcf > 1) { u64 k = ks[w1], kl = kls[w1]; anyk |= m1 & k; anyu |= m1 & ~(k | kl); }
                if (wcf > 2) { u64 k = ks[w2], kl = kls[w2]; anyk |= m2 & k; anyu |= m2 & ~(k | kl); }
                if (wcf > 3) { u64 k = ks[w3], kl = kls[w3]; anyk |= m3 & k; anyu |= m3 & ~(k | kl); }
                if (wcf > 4) { u64 k = ks[w4], kl = kls[w4]; anyk |= m4 & k; anyu |= m4 & ~(k | kl); }
                if (wcf > 5) { u64 k = ks[w5], kl = kls[w5]; anyk |= m5 & k; anyu |= m5 & ~(k | kl); }
                for (u32 kk = 6; kk < wcf; ++kk) {
                    u32 Wo = ovw[(size_t)i * CAPO + (kk - 6)];
                    u64 mo = ovm[(size_t)i * CAPO + (kk - 6)];
                    u64 k = ks[Wo], kl = kls[Wo];
                    anyk |= mo & k; anyu |= mo & ~(k | kl);
                }
                if (anyk) {
                    undec = false;
                    atomicOr(&killedg[myw], mybit);
                    atomicOr(&kls[myw], mybit);
                } else if (!anyu) {
                    undec = false;
                    keepfl = true;
                    atomicOr(&keptg[myw], mybit);
                    atomicOr(&ks[myw], mybit);
                }
            }
            __syncthreads();
        }
        if (undec) atomicAdd(&nund, 1);
        __syncthreads();
        if (nund == 0) break;
    }

    int og = orig_of(i);
    float m = keepfl ? 1.0f : 0.0f;
    float4 bx = boxes[og];
    float s = score[og];
    out[(size_t)og * 5 + 0] = __fmul_rn(bx.x, m);
    out[(size_t)og * 5 + 1] = __fmul_rn(bx.y, m);
    out[(size_t)og * 5 + 2] = __fmul_rn(bx.z, m);
    out[(size_t)og * 5 + 3] = __fmul_rn(bx.w, m);
    out[(size_t)og * 5 + 4] = __fmul_rn(s, m);
}

extern "C" void kernel_launch(void* const* d_in, const int* in_sizes, int n_in,
                              void* d_out, int out_size, void* d_ws, size_t ws_size,
                              hipStream_t stream) {
    const float4* loc = (const float4*)d_in[0];
    const float* cls = (const float*)d_in[1];
    char* ws = (char*)d_ws;

    float4* boxes   = (float4*)(ws + 0);           // 196608
    float*  score   = (float*) (ws + 196608);      // 49152
    float4* pbox    = (float4*)(ws + 245760);      // 196608
    u64*    pkey    = (u64*)   (ws + 442368);      // 98304
    u64*    rec8    = (u64*)   (ws + 540672);      // 786432
    u64*    keptg   = (u64*)   (ws + 1327104);     // 1536
    u64*    killedg = (u64*)   (ws + 1328640);     // 1536
    float4* wbg     = (float4*)(ws + 1330176);     // 3072
    u32*    ocnt    = (u32*)   (ws + 1333248);     // 768
    u16*    olist   = (u16*)   (ws + 1334080);     // 24576 (192*64 u16)
    u8*     ovw     = (u8*)    (ws + 1358656);     // 12582912
    u64*    ovm     = (u64*)   (ws + 13941568);    // 100663296 (end ~114.6MB; ws ~256MB)
    float*  out     = (float*)d_out;

    decode_kernel<<<48, 256, 0, stream>>>(loc, cls, boxes, score, pbox, pkey, rec8,
                                          wbg, ocnt, olist);
    pairs_kernel<<<768, 512, 0, stream>>>(pbox, pkey, rec8, ovw, ovm,
                                          wbg, ocnt, olist, keptg, killedg);
    solve_kernel<<<12, 1024, 0, stream>>>(rec8, ovw, ovm, boxes, score, pkey,
                                          keptg, killedg, out);
}